// Round 12
// baseline (241.027 us; speedup 1.0000x reference)
//
#include <hip/hip_runtime.h>
#include <math.h>

#define HID 64
#define KB 9            // NUM_BINS - 1
#define NB 10
#define NTOT (128 * 20000)
#define BLOCK 256
#define LEAKY 0.01f
#define RSTRIDE 20      // floats per region row (9 A + 9 C + 2 pad) = 5 f4s
#define SENT 3.0e38f
#define LOG2E 1.44269504088896f

// bucket LUT for region search
#define NBUK 2048
#define BLO (-6.0f)
#define BSCALE (2048.0f / 12.0f)

#define TAB_U32 (128 + 65 * RSTRIDE)      // 1428 u32: 128 thresholds + 65 rows
#define SD_U32 (TAB_U32 + NBUK / 4)       // + 512 u32 of u8 buckets = 1940 (= 485 f4)
#define CNT_U32 2048                      // list counter (u32 index in ws)
#define LIST_U32 2056                     // list base (8B aligned)
#define WS_BYTES (LIST_U32 * 4 + (size_t)NTOT * 8)   // worst-case all-nonzero list

typedef float v4f __attribute__((ext_vector_type(4)));
typedef float v2f __attribute__((ext_vector_type(2)));

// ---------------- setup: 97 blocks x 64 threads (R9 structure + counter zero) ----------------
__global__ __launch_bounds__(64) void setup_kernel(
    const float* __restrict__ W1, const float* __restrict__ b1,
    const float* __restrict__ W2, const float* __restrict__ b2,
    float* __restrict__ ws)
{
    __shared__ float t_lds[HID], w_lds[HID], b_lds[HID], tsrt[HID];
    __shared__ float w2_lds[HID * KB];
    __shared__ float red[18 * 65];   // rows padded to 65 -> conflict-free reduce

    const int j = threadIdx.x;       // unit index (original order)
    const int blk = blockIdx.x;
    if (blk == 0 && j == 0) ((unsigned*)ws)[CNT_U32] = 0;   // list counter (re-zeroed every call)
    const float w = W1[j], b = b1[j];
    const float t = (w != 0.0f) ? (-b / w) : -SENT;  // w==0: constant sign, park at -inf
    t_lds[j] = t; w_lds[j] = w; b_lds[j] = b;
    if (blk < 65) {
        #pragma unroll
        for (int q = j; q < HID * KB; q += 64) w2_lds[q] = W2[q];
    }
    __syncthreads();

    int rank = 0;                    // rank sort (unique ranks via index tiebreak)
    for (int i = 0; i < HID; ++i) {
        float ti = t_lds[i];
        rank += (ti < t || (ti == t && i < j)) ? 1 : 0;
    }
    tsrt[rank] = t;
    __syncthreads();

    if (blk >= 65) {                 // bucket fill
        const int bb = (blk - 65) * 64 + j;
        const float edge = BLO + ((float)bb - 0.5f) * (1.0f / BSCALE);  // half-bucket margin
        int cnt = 0;
        for (int i = 0; i < HID; ++i) cnt += (tsrt[i] <= edge) ? 1 : 0;
        ((unsigned char*)(ws + TAB_U32))[bb] = (bb == 0) ? 0 : (unsigned char)cnt;
        return;
    }

    const int r = blk;               // region index 0..64
    float xm;                        // point strictly inside region r
    if (r == 0)        xm = tsrt[0] - 1.0f;
    else if (r == HID) xm = tsrt[HID - 1] + 1.0f;
    else               xm = 0.5f * (tsrt[r - 1] + tsrt[r]);

    const float s = (fmaf(w, xm, b) >= 0.0f) ? 1.0f : LEAKY;
    #pragma unroll
    for (int k = 0; k < KB; ++k) {
        const float w2s = w2_lds[j * KB + k] * s;
        red[(2 * k) * 65 + j]     = w2s * w;   // A contribution
        red[(2 * k + 1) * 65 + j] = w2s * b;   // C contribution
    }
    __syncthreads();

    if (j < 18) {   // threads 0..17 each sum one row of 64 (deterministic order)
        float acc = 0.0f;
        for (int i = 0; i < HID; ++i) acc += red[j * 65 + i];
        const int k = j >> 1;
        if (j & 1) ws[128 + r * RSTRIDE + KB + k] = (acc + b2[k]) * LOG2E;  // C'
        else       ws[128 + r * RSTRIDE + k]      = acc * LOG2E;            // A'
    }
    if (r == 0) { ws[j] = tsrt[j]; ws[64 + j] = SENT; }
}

// ---------------- kernel 2: fill-like stream (no LDS, no barriers) ----------------
// Thread t: 4 elements. Issues 10 default-prob f4 stores FIRST (dependency-free),
// then expr f4 load -> mask f4 store -> wave-scan + one wave atomicAdd to append
// (idx,val) u64s to the ws list for kernel 3.
__global__ __launch_bounds__(BLOCK) void stream_kernel(
    const float* __restrict__ expr, float* __restrict__ ws,
    float* __restrict__ out)
{
    const int t = blockIdx.x * BLOCK + threadIdx.x;   // global thread, 4 elems each
    const int lane = threadIdx.x & 63;

    // default probs: thread's f4 j covers floats 40t+4j..+3; 1 at (4j+c)%10==0
    v4f* gp = (v4f*)out + (size_t)t * 10;
    #pragma unroll
    for (int j = 0; j < 10; ++j) {
        const int r5 = j % 5;
        const v4f v = {r5 == 0 ? 1.0f : 0.0f, 0.0f, r5 == 2 ? 1.0f : 0.0f, 0.0f};
        gp[j] = v;
    }

    // expr + mask
    const v4f xv = ((const v4f*)expr)[t];
    const float xr[4] = {xv.x, xv.y, xv.z, xv.w};
    const v4f mv = {xr[0] != 0.f ? 1.f : 0.f, xr[1] != 0.f ? 1.f : 0.f,
                    xr[2] != 0.f ? 1.f : 0.f, xr[3] != 0.f ? 1.f : 0.f};
    ((v4f*)(out + (size_t)NTOT * NB))[t] = mv;

    // wave-compacted append of nonzeros
    int c = 0;
    #pragma unroll
    for (int j = 0; j < 4; ++j) c += (xr[j] != 0.0f) ? 1 : 0;
    int incl = c;
    #pragma unroll
    for (int d = 1; d < 64; d <<= 1) {
        int n = __shfl_up(incl, d, 64);
        if (lane >= d) incl += n;
    }
    const int wtotal = __shfl(incl, 63, 64);
    unsigned wbase = 0;
    if (lane == 63 && wtotal > 0)
        wbase = atomicAdd((unsigned*)ws + CNT_U32, (unsigned)wtotal);
    wbase = __shfl((int)wbase, 63, 64);

    unsigned long long* list = (unsigned long long*)(ws + LIST_U32);
    int off = (int)wbase + (incl - c);
    #pragma unroll
    for (int j = 0; j < 4; ++j) {
        if (xr[j] != 0.0f) {
            const unsigned eidx = 4u * (unsigned)t + (unsigned)j;
            list[off++] = ((unsigned long long)eidx << 32) | (unsigned long long)__float_as_uint(xr[j]);
        }
    }
}

// ---------------- kernel 3: scatter softmax over the compacted list ----------------
__global__ __launch_bounds__(BLOCK) void scatter_kernel(
    const float* __restrict__ ws, float* __restrict__ out)
{
    const unsigned count = ((const unsigned*)ws)[CNT_U32];
    if ((unsigned)blockIdx.x * BLOCK >= count) return;   // zero-iteration blocks skip staging

    __shared__ __align__(16) unsigned int sdata[SD_U32];   // ts | tab | buckets
    const int tid = threadIdx.x;
    #pragma unroll
    for (int q = tid; q < SD_U32 / 4; q += BLOCK)
        ((v4f*)sdata)[q] = ((const v4f*)ws)[q];
    __syncthreads();

    const float* ts  = (const float*)sdata;
    const float* tab = (const float*)sdata + 128;
    const unsigned char* buk = (const unsigned char*)(sdata + TAB_U32);
    const unsigned long long* list = (const unsigned long long*)(ws + LIST_U32);

    for (unsigned i = blockIdx.x * BLOCK + tid; i < count; i += gridDim.x * BLOCK) {
        const unsigned long long pk = list[i];
        const unsigned e = (unsigned)(pk >> 32);
        const float xe = __uint_as_float((unsigned)pk);
        // bucket start (guaranteed <= region(xe)), then exact forward scan
        const float fb = fminf(2047.0f, fmaxf(0.0f, (xe - BLO) * BSCALE));
        int idx = buk[(int)fb];
        while (ts[idx] <= xe) ++idx;   // ts padded with SENT -> terminates, idx<=64
        const v4f* rowv = (const v4f*)(tab + idx * RSTRIDE);
        const v4f r0 = rowv[0], r1 = rowv[1], r2 = rowv[2], r3 = rowv[3], r4 = rowv[4];
        const float A[KB] = {r0.x, r0.y, r0.z, r0.w, r1.x, r1.y, r1.z, r1.w, r2.x};
        const float C[KB] = {r2.y, r2.z, r2.w, r3.x, r3.y, r3.z, r3.w, r4.x, r4.y};
        float lg[KB];   // base-2 logits (table pre-scaled by log2e)
        #pragma unroll
        for (int k = 0; k < KB; ++k) lg[k] = fmaf(A[k], xe, C[k]);
        float m = lg[0];
        #pragma unroll
        for (int k = 1; k < KB; ++k) m = fmaxf(m, lg[k]);
        float p[KB];
        float s = 0.0f;
        #pragma unroll
        for (int k = 0; k < KB; ++k) { p[k] = exp2f(lg[k] - m); s += p[k]; }
        const float rcp = __frcp_rn(s);
        v2f* po = (v2f*)(out + (size_t)e * NB);   // 8B-aligned (40e bytes)
        po[0] = (v2f){0.0f,       p[0] * rcp};
        po[1] = (v2f){p[1] * rcp, p[2] * rcp};
        po[2] = (v2f){p[3] * rcp, p[4] * rcp};
        po[3] = (v2f){p[5] * rcp, p[6] * rcp};
        po[4] = (v2f){p[7] * rcp, p[8] * rcp};
    }
}

// ---------------- fallback if d_ws too small: self-contained dense kernel ----------------
__global__ __launch_bounds__(BLOCK) void fused_kernel(
    const float* __restrict__ expr,
    const float* __restrict__ W1, const float* __restrict__ b1,
    const float* __restrict__ W2, const float* __restrict__ b2,
    float* __restrict__ out)
{
    __shared__ float ts[128];
    __shared__ float tab[65 * RSTRIDE];
    __shared__ float st[HID], sw[HID], sb[HID], tsrt[HID];
    const int tid = threadIdx.x;
    if (tid < HID) {
        float w = W1[tid], b = b1[tid];
        st[tid] = (w != 0.0f) ? (-b / w) : -SENT;
        sw[tid] = w; sb[tid] = b;
    }
    __syncthreads();
    if (tid < HID) {
        float t = st[tid];
        int r = 0;
        for (int i = 0; i < HID; ++i) {
            float ti = st[i];
            r += (ti < t || (ti == t && i < tid)) ? 1 : 0;
        }
        tsrt[r] = t;
    }
    __syncthreads();
    if (tid < 128) ts[tid] = (tid < HID) ? tsrt[tid] : SENT;
    for (int item = tid; item < 65 * KB; item += BLOCK) {
        int r = item / KB, k = item - r * KB;
        float xm;
        if (r == 0)        xm = tsrt[0] - 1.0f;
        else if (r == HID) xm = tsrt[HID - 1] + 1.0f;
        else               xm = 0.5f * (tsrt[r - 1] + tsrt[r]);
        float A = 0.0f, C = b2[k];
        for (int j = 0; j < HID; ++j) {
            float w = sw[j], bb = sb[j];
            float s = (fmaf(w, xm, bb) >= 0.0f) ? 1.0f : LEAKY;
            float w2s = W2[j * KB + k] * s;
            A = fmaf(w2s, w, A);
            C = fmaf(w2s, bb, C);
        }
        tab[r * RSTRIDE + k] = A;
        tab[r * RSTRIDE + KB + k] = C;
    }
    __syncthreads();
    const int i0 = (blockIdx.x * BLOCK + tid) * 2;
    const float2 xv = *(const float2*)(expr + i0);
    float x[2] = {xv.x, xv.y};
    float o[2 * NB]; float msk[2];
    #pragma unroll
    for (int e = 0; e < 2; ++e) {
        const float xe = x[e];
        int idx = 0;
        #pragma unroll
        for (int s = 64; s >= 1; s >>= 1) idx += (ts[idx + s - 1] <= xe) ? s : 0;
        const float* row = tab + idx * RSTRIDE;
        float lg[KB];
        #pragma unroll
        for (int k = 0; k < KB; ++k) lg[k] = fmaf(row[k], xe, row[KB + k]);
        float m = lg[0];
        #pragma unroll
        for (int k = 1; k < KB; ++k) m = fmaxf(m, lg[k]);
        float p[KB]; float s = 0.0f;
        #pragma unroll
        for (int k = 0; k < KB; ++k) { p[k] = __expf(lg[k] - m); s += p[k]; }
        const float rcp = __frcp_rn(s);
        const bool nz = (xe != 0.0f);
        msk[e] = nz ? 1.0f : 0.0f;
        o[e * NB] = nz ? 0.0f : 1.0f;
        #pragma unroll
        for (int k = 0; k < KB; ++k) o[e * NB + 1 + k] = nz ? p[k] * rcp : 0.0f;
    }
    float* dst = out + (size_t)i0 * NB;
    #pragma unroll
    for (int q = 0; q < 5; ++q) ((float4*)dst)[q] = ((const float4*)o)[q];
    *(float2*)(out + (size_t)NTOT * NB + i0) = make_float2(msk[0], msk[1]);
}

extern "C" void kernel_launch(void* const* d_in, const int* in_sizes, int n_in,
                              void* d_out, int out_size, void* d_ws, size_t ws_size,
                              hipStream_t stream) {
    const float* expr = (const float*)d_in[0];
    const float* W1   = (const float*)d_in[1];
    const float* b1   = (const float*)d_in[2];
    const float* W2   = (const float*)d_in[3];
    const float* b2   = (const float*)d_in[4];
    float* out = (float*)d_out;

    if (ws_size >= WS_BYTES) {
        float* ws = (float*)d_ws;
        setup_kernel<<<65 + NBUK / 64, 64, 0, stream>>>(W1, b1, W2, b2, ws);
        stream_kernel<<<NTOT / (BLOCK * 4), BLOCK, 0, stream>>>(expr, ws, out);   // 2500 blocks
        scatter_kernel<<<2560, BLOCK, 0, stream>>>(ws, out);                      // grid-stride over count
    } else {
        fused_kernel<<<NTOT / (BLOCK * 2), BLOCK, 0, stream>>>(expr, W1, b1, W2, b2, out);
    }
}

// Round 13
// 239.576 us; speedup vs baseline: 1.0061x; 1.0061x over previous
//
#include <hip/hip_runtime.h>
#include <math.h>

#define HID 64
#define KB 9            // NUM_BINS - 1
#define NB 10
#define NTOT (128 * 20000)
#define BLOCK 256
#define LEAKY 0.01f
#define RSTRIDE 20      // floats per region row (9 A + 9 C + 2 pad) = 5 f4s
#define SENT 3.0e38f
#define LOG2E 1.44269504088896f

// bucket LUT for region search
#define NBUK 2048
#define BLO (-6.0f)
#define BSCALE (2048.0f / 12.0f)

#define TAB_U32 (128 + 65 * RSTRIDE)      // 1428 u32: 128 thresholds + 65 rows
#define SD_U32 (TAB_U32 + NBUK / 4)       // + 512 u32 of u8 buckets = 1940 (= 485 f4)
#define CNT_U32 2048                      // list counter (u32 index in ws)
#define LIST_U32 2056                     // list base (8B aligned)
#define WS_BYTES (LIST_U32 * 4 + (size_t)NTOT * 8)   // worst-case all-nonzero list

typedef float v4f __attribute__((ext_vector_type(4)));
typedef float v2f __attribute__((ext_vector_type(2)));

// ---------------- setup: 97 blocks x 64 threads (R9 structure + counter zero) ----------------
__global__ __launch_bounds__(64) void setup_kernel(
    const float* __restrict__ W1, const float* __restrict__ b1,
    const float* __restrict__ W2, const float* __restrict__ b2,
    float* __restrict__ ws)
{
    __shared__ float t_lds[HID], w_lds[HID], b_lds[HID], tsrt[HID];
    __shared__ float w2_lds[HID * KB];
    __shared__ float red[18 * 65];   // rows padded to 65 -> conflict-free reduce

    const int j = threadIdx.x;       // unit index (original order)
    const int blk = blockIdx.x;
    if (blk == 0 && j == 0) ((unsigned*)ws)[CNT_U32] = 0;   // list counter (re-zeroed every call)
    const float w = W1[j], b = b1[j];
    const float t = (w != 0.0f) ? (-b / w) : -SENT;  // w==0: constant sign, park at -inf
    t_lds[j] = t; w_lds[j] = w; b_lds[j] = b;
    if (blk < 65) {
        #pragma unroll
        for (int q = j; q < HID * KB; q += 64) w2_lds[q] = W2[q];
    }
    __syncthreads();

    int rank = 0;                    // rank sort (unique ranks via index tiebreak)
    for (int i = 0; i < HID; ++i) {
        float ti = t_lds[i];
        rank += (ti < t || (ti == t && i < j)) ? 1 : 0;
    }
    tsrt[rank] = t;
    __syncthreads();

    if (blk >= 65) {                 // bucket fill
        const int bb = (blk - 65) * 64 + j;
        const float edge = BLO + ((float)bb - 0.5f) * (1.0f / BSCALE);  // half-bucket margin
        int cnt = 0;
        for (int i = 0; i < HID; ++i) cnt += (tsrt[i] <= edge) ? 1 : 0;
        ((unsigned char*)(ws + TAB_U32))[bb] = (bb == 0) ? 0 : (unsigned char)cnt;
        return;
    }

    const int r = blk;               // region index 0..64
    float xm;                        // point strictly inside region r
    if (r == 0)        xm = tsrt[0] - 1.0f;
    else if (r == HID) xm = tsrt[HID - 1] + 1.0f;
    else               xm = 0.5f * (tsrt[r - 1] + tsrt[r]);

    const float s = (fmaf(w, xm, b) >= 0.0f) ? 1.0f : LEAKY;
    #pragma unroll
    for (int k = 0; k < KB; ++k) {
        const float w2s = w2_lds[j * KB + k] * s;
        red[(2 * k) * 65 + j]     = w2s * w;   // A contribution
        red[(2 * k + 1) * 65 + j] = w2s * b;   // C contribution
    }
    __syncthreads();

    if (j < 18) {   // threads 0..17 each sum one row of 64 (deterministic order)
        float acc = 0.0f;
        for (int i = 0; i < HID; ++i) acc += red[j * 65 + i];
        const int k = j >> 1;
        if (j & 1) ws[128 + r * RSTRIDE + KB + k] = (acc + b2[k]) * LOG2E;  // C'
        else       ws[128 + r * RSTRIDE + k]      = acc * LOG2E;            // A'
    }
    if (r == 0) { ws[j] = tsrt[j]; ws[64 + j] = SENT; }
}

// ---------------- kernel 2: fill-like stream (no LDS, no barriers) ----------------
// Block owns a contiguous 1024-elem tile. ALL stores lane-contiguous f4
// (R12 bug: thread-major t*10 scattered each wave store over 160 cache
// lines -> 988 GB/s; lane-major g=q*BLOCK+tid is the fill pattern).
__global__ __launch_bounds__(BLOCK) void stream_kernel(
    const float* __restrict__ expr, float* __restrict__ ws,
    float* __restrict__ out)
{
    const int tid = threadIdx.x;
    const int bt = blockIdx.x * BLOCK + tid;   // global thread, 4 elems each
    const int lane = tid & 63;

    // expr load issued first: latency hides under the default-store burst
    const v4f xv = ((const v4f*)expr)[bt];

    // default probs: block tile = 1024 elems = 2560 f4s, lane-major.
    // f4 g covers floats 4g..4g+3 of the tile; tile base is 10240-float
    // aligned so float (4g+c) has output index %10 == (4g+c)%10:
    // g%5==0 -> {1,0,0,0}; g%5==2 -> {0,0,1,0}; else zeros.
    v4f* gout = (v4f*)out + (size_t)blockIdx.x * (BLOCK * 10);
    #pragma unroll
    for (int q = 0; q < 10; ++q) {
        const int g = q * BLOCK + tid;
        const int r5 = g % 5;                  // = (q+tid)%5, compiler folds
        const v4f v = {r5 == 0 ? 1.0f : 0.0f, 0.0f, r5 == 2 ? 1.0f : 0.0f, 0.0f};
        gout[g] = v;
    }

    // mask: lane-contiguous f4
    const float xr[4] = {xv.x, xv.y, xv.z, xv.w};
    const v4f mv = {xr[0] != 0.f ? 1.f : 0.f, xr[1] != 0.f ? 1.f : 0.f,
                    xr[2] != 0.f ? 1.f : 0.f, xr[3] != 0.f ? 1.f : 0.f};
    ((v4f*)(out + (size_t)NTOT * NB))[bt] = mv;

    // wave-compacted append of nonzeros to the ws list
    int c = 0;
    #pragma unroll
    for (int j = 0; j < 4; ++j) c += (xr[j] != 0.0f) ? 1 : 0;
    int incl = c;
    #pragma unroll
    for (int d = 1; d < 64; d <<= 1) {
        int n = __shfl_up(incl, d, 64);
        if (lane >= d) incl += n;
    }
    const int wtotal = __shfl(incl, 63, 64);
    unsigned wbase = 0;
    if (lane == 63 && wtotal > 0)
        wbase = atomicAdd((unsigned*)ws + CNT_U32, (unsigned)wtotal);
    wbase = __shfl((int)wbase, 63, 64);

    unsigned long long* list = (unsigned long long*)(ws + LIST_U32);
    int off = (int)wbase + (incl - c);
    #pragma unroll
    for (int j = 0; j < 4; ++j) {
        if (xr[j] != 0.0f) {
            const unsigned eidx = 4u * (unsigned)bt + (unsigned)j;
            list[off++] = ((unsigned long long)eidx << 32) | (unsigned long long)__float_as_uint(xr[j]);
        }
    }
}

// ---------------- kernel 3: scatter softmax over the compacted list ----------------
// Dispatch boundary provides defaults->overwrite WAW ordering.
__global__ __launch_bounds__(BLOCK) void scatter_kernel(
    const float* __restrict__ ws, float* __restrict__ out)
{
    const unsigned count = ((const unsigned*)ws)[CNT_U32];
    if ((unsigned)blockIdx.x * BLOCK >= count) return;   // zero-iteration blocks skip staging

    __shared__ __align__(16) unsigned int sdata[SD_U32];   // ts | tab | buckets
    const int tid = threadIdx.x;
    #pragma unroll
    for (int q = tid; q < SD_U32 / 4; q += BLOCK)
        ((v4f*)sdata)[q] = ((const v4f*)ws)[q];
    __syncthreads();

    const float* ts  = (const float*)sdata;
    const float* tab = (const float*)sdata + 128;
    const unsigned char* buk = (const unsigned char*)(sdata + TAB_U32);
    const unsigned long long* list = (const unsigned long long*)(ws + LIST_U32);

    for (unsigned i = blockIdx.x * BLOCK + tid; i < count; i += gridDim.x * BLOCK) {
        const unsigned long long pk = list[i];
        const unsigned e = (unsigned)(pk >> 32);
        const float xe = __uint_as_float((unsigned)pk);
        // bucket start (guaranteed <= region(xe)), then exact forward scan
        const float fb = fminf(2047.0f, fmaxf(0.0f, (xe - BLO) * BSCALE));
        int idx = buk[(int)fb];
        while (ts[idx] <= xe) ++idx;   // ts padded with SENT -> terminates, idx<=64
        const v4f* rowv = (const v4f*)(tab + idx * RSTRIDE);
        const v4f r0 = rowv[0], r1 = rowv[1], r2 = rowv[2], r3 = rowv[3], r4 = rowv[4];
        const float A[KB] = {r0.x, r0.y, r0.z, r0.w, r1.x, r1.y, r1.z, r1.w, r2.x};
        const float C[KB] = {r2.y, r2.z, r2.w, r3.x, r3.y, r3.z, r3.w, r4.x, r4.y};
        float lg[KB];   // base-2 logits (table pre-scaled by log2e)
        #pragma unroll
        for (int k = 0; k < KB; ++k) lg[k] = fmaf(A[k], xe, C[k]);
        float m = lg[0];
        #pragma unroll
        for (int k = 1; k < KB; ++k) m = fmaxf(m, lg[k]);
        float p[KB];
        float s = 0.0f;
        #pragma unroll
        for (int k = 0; k < KB; ++k) { p[k] = exp2f(lg[k] - m); s += p[k]; }
        const float rcp = __frcp_rn(s);
        v2f* po = (v2f*)(out + (size_t)e * NB);   // 8B-aligned (40e bytes)
        po[0] = (v2f){0.0f,       p[0] * rcp};
        po[1] = (v2f){p[1] * rcp, p[2] * rcp};
        po[2] = (v2f){p[3] * rcp, p[4] * rcp};
        po[3] = (v2f){p[5] * rcp, p[6] * rcp};
        po[4] = (v2f){p[7] * rcp, p[8] * rcp};
    }
}

// ---------------- fallback if d_ws too small: self-contained dense kernel ----------------
__global__ __launch_bounds__(BLOCK) void fused_kernel(
    const float* __restrict__ expr,
    const float* __restrict__ W1, const float* __restrict__ b1,
    const float* __restrict__ W2, const float* __restrict__ b2,
    float* __restrict__ out)
{
    __shared__ float ts[128];
    __shared__ float tab[65 * RSTRIDE];
    __shared__ float st[HID], sw[HID], sb[HID], tsrt[HID];
    const int tid = threadIdx.x;
    if (tid < HID) {
        float w = W1[tid], b = b1[tid];
        st[tid] = (w != 0.0f) ? (-b / w) : -SENT;
        sw[tid] = w; sb[tid] = b;
    }
    __syncthreads();
    if (tid < HID) {
        float t = st[tid];
        int r = 0;
        for (int i = 0; i < HID; ++i) {
            float ti = st[i];
            r += (ti < t || (ti == t && i < tid)) ? 1 : 0;
        }
        tsrt[r] = t;
    }
    __syncthreads();
    if (tid < 128) ts[tid] = (tid < HID) ? tsrt[tid] : SENT;
    for (int item = tid; item < 65 * KB; item += BLOCK) {
        int r = item / KB, k = item - r * KB;
        float xm;
        if (r == 0)        xm = tsrt[0] - 1.0f;
        else if (r == HID) xm = tsrt[HID - 1] + 1.0f;
        else               xm = 0.5f * (tsrt[r - 1] + tsrt[r]);
        float A = 0.0f, C = b2[k];
        for (int j = 0; j < HID; ++j) {
            float w = sw[j], bb = sb[j];
            float s = (fmaf(w, xm, bb) >= 0.0f) ? 1.0f : LEAKY;
            float w2s = W2[j * KB + k] * s;
            A = fmaf(w2s, w, A);
            C = fmaf(w2s, bb, C);
        }
        tab[r * RSTRIDE + k] = A;
        tab[r * RSTRIDE + KB + k] = C;
    }
    __syncthreads();
    const int i0 = (blockIdx.x * BLOCK + tid) * 2;
    const float2 xv = *(const float2*)(expr + i0);
    float x[2] = {xv.x, xv.y};
    float o[2 * NB]; float msk[2];
    #pragma unroll
    for (int e = 0; e < 2; ++e) {
        const float xe = x[e];
        int idx = 0;
        #pragma unroll
        for (int s = 64; s >= 1; s >>= 1) idx += (ts[idx + s - 1] <= xe) ? s : 0;
        const float* row = tab + idx * RSTRIDE;
        float lg[KB];
        #pragma unroll
        for (int k = 0; k < KB; ++k) lg[k] = fmaf(row[k], xe, row[KB + k]);
        float m = lg[0];
        #pragma unroll
        for (int k = 1; k < KB; ++k) m = fmaxf(m, lg[k]);
        float p[KB]; float s = 0.0f;
        #pragma unroll
        for (int k = 0; k < KB; ++k) { p[k] = __expf(lg[k] - m); s += p[k]; }
        const float rcp = __frcp_rn(s);
        const bool nz = (xe != 0.0f);
        msk[e] = nz ? 1.0f : 0.0f;
        o[e * NB] = nz ? 0.0f : 1.0f;
        #pragma unroll
        for (int k = 0; k < KB; ++k) o[e * NB + 1 + k] = nz ? p[k] * rcp : 0.0f;
    }
    float* dst = out + (size_t)i0 * NB;
    #pragma unroll
    for (int q = 0; q < 5; ++q) ((float4*)dst)[q] = ((const float4*)o)[q];
    *(float2*)(out + (size_t)NTOT * NB + i0) = make_float2(msk[0], msk[1]);
}

extern "C" void kernel_launch(void* const* d_in, const int* in_sizes, int n_in,
                              void* d_out, int out_size, void* d_ws, size_t ws_size,
                              hipStream_t stream) {
    const float* expr = (const float*)d_in[0];
    const float* W1   = (const float*)d_in[1];
    const float* b1   = (const float*)d_in[2];
    const float* W2   = (const float*)d_in[3];
    const float* b2   = (const float*)d_in[4];
    float* out = (float*)d_out;

    if (ws_size >= WS_BYTES) {
        float* ws = (float*)d_ws;
        setup_kernel<<<65 + NBUK / 64, 64, 0, stream>>>(W1, b1, W2, b2, ws);
        stream_kernel<<<NTOT / (BLOCK * 4), BLOCK, 0, stream>>>(expr, ws, out);   // 2500 blocks
        scatter_kernel<<<2560, BLOCK, 0, stream>>>(ws, out);                      // grid-stride over count
    } else {
        fused_kernel<<<NTOT / (BLOCK * 2), BLOCK, 0, stream>>>(expr, W1, b1, W2, b2, out);
    }
}

// Round 14
// 147.786 us; speedup vs baseline: 1.6309x; 1.6211x over previous
//
#include <hip/hip_runtime.h>
#include <math.h>

#define HID 64
#define KB 9            // NUM_BINS - 1
#define NB 10
#define NTOT (128 * 20000)
#define BLOCK 256
#define LEAKY 0.01f
#define RSTRIDE 20      // floats per region row (9 A + 9 C + 2 pad) = 5 f4s
#define SENT 3.0e38f
#define LOG2E 1.44269504088896f

// bucket LUT for region search
#define NBUK 2048
#define BLO (-6.0f)
#define BSCALE (2048.0f / 12.0f)

#define TAB_U32 (128 + 65 * RSTRIDE)      // 1428 u32: 128 thresholds + 65 rows
#define SD_U32 (TAB_U32 + NBUK / 4)       // + 512 u32 of u8 buckets = 1940 (= 485 f4)
#define NSEG (NTOT / 256)                 // 10000 wave segments (256 elems each)
#define CNT_BASE 4096                     // u32 offset of counts[NSEG]
#define LIST_BASE 16384                   // u32 offset of list (u64 x NSEG*256)
#define WS_BYTES ((size_t)(LIST_BASE + NSEG * 256 * 2) * 4)   // ~20.5 MB

typedef float v4f __attribute__((ext_vector_type(4)));
typedef float v2f __attribute__((ext_vector_type(2)));

// ---------------- setup: 97 blocks x 64 threads (unchanged) ----------------
__global__ __launch_bounds__(64) void setup_kernel(
    const float* __restrict__ W1, const float* __restrict__ b1,
    const float* __restrict__ W2, const float* __restrict__ b2,
    float* __restrict__ ws)
{
    __shared__ float t_lds[HID], w_lds[HID], b_lds[HID], tsrt[HID];
    __shared__ float w2_lds[HID * KB];
    __shared__ float red[18 * 65];   // rows padded to 65 -> conflict-free reduce

    const int j = threadIdx.x;       // unit index (original order)
    const int blk = blockIdx.x;
    const float w = W1[j], b = b1[j];
    const float t = (w != 0.0f) ? (-b / w) : -SENT;  // w==0: constant sign, park at -inf
    t_lds[j] = t; w_lds[j] = w; b_lds[j] = b;
    if (blk < 65) {
        #pragma unroll
        for (int q = j; q < HID * KB; q += 64) w2_lds[q] = W2[q];
    }
    __syncthreads();

    int rank = 0;                    // rank sort (unique ranks via index tiebreak)
    for (int i = 0; i < HID; ++i) {
        float ti = t_lds[i];
        rank += (ti < t || (ti == t && i < j)) ? 1 : 0;
    }
    tsrt[rank] = t;
    __syncthreads();

    if (blk >= 65) {                 // bucket fill
        const int bb = (blk - 65) * 64 + j;
        const float edge = BLO + ((float)bb - 0.5f) * (1.0f / BSCALE);  // half-bucket margin
        int cnt = 0;
        for (int i = 0; i < HID; ++i) cnt += (tsrt[i] <= edge) ? 1 : 0;
        ((unsigned char*)(ws + TAB_U32))[bb] = (bb == 0) ? 0 : (unsigned char)cnt;
        return;
    }

    const int r = blk;               // region index 0..64
    float xm;                        // point strictly inside region r
    if (r == 0)        xm = tsrt[0] - 1.0f;
    else if (r == HID) xm = tsrt[HID - 1] + 1.0f;
    else               xm = 0.5f * (tsrt[r - 1] + tsrt[r]);

    const float s = (fmaf(w, xm, b) >= 0.0f) ? 1.0f : LEAKY;
    #pragma unroll
    for (int k = 0; k < KB; ++k) {
        const float w2s = w2_lds[j * KB + k] * s;
        red[(2 * k) * 65 + j]     = w2s * w;   // A contribution
        red[(2 * k + 1) * 65 + j] = w2s * b;   // C contribution
    }
    __syncthreads();

    if (j < 18) {   // threads 0..17 each sum one row of 64 (deterministic order)
        float acc = 0.0f;
        for (int i = 0; i < HID; ++i) acc += red[j * 65 + i];
        const int k = j >> 1;
        if (j & 1) ws[128 + r * RSTRIDE + KB + k] = (acc + b2[k]) * LOG2E;  // C'
        else       ws[128 + r * RSTRIDE + k]      = acc * LOG2E;            // A'
    }
    if (r == 0) { ws[j] = tsrt[j]; ws[64 + j] = SENT; }
}

// ---------------- kernel 2: fill-like stream — NO atomics, NO barriers, NO LDS ----------------
// R13 lesson: 10,000 same-address returning atomicAdds serialized the whole
// dispatch (~12ns each). Now each wave owns a fixed 256-elem segment and a
// fixed list slice — zero cross-wave communication.
__global__ __launch_bounds__(BLOCK) void stream_kernel(
    const float* __restrict__ expr, float* __restrict__ ws,
    float* __restrict__ out)
{
    const int tid = threadIdx.x;
    const int bt = blockIdx.x * BLOCK + tid;   // global thread, 4 elems each
    const int lane = tid & 63;
    const int seg = bt >> 6;                   // global wave id = segment id

    // expr load issued first: latency hides under the default-store burst
    const v4f xv = ((const v4f*)expr)[bt];

    // default probs: block tile = 1024 elems = 2560 f4s, lane-major.
    // g%5==0 -> {1,0,0,0}; g%5==2 -> {0,0,1,0}; else zeros (tile base 10240-aligned).
    v4f* gout = (v4f*)out + (size_t)blockIdx.x * (BLOCK * 10);
    #pragma unroll
    for (int q = 0; q < 10; ++q) {
        const int g = q * BLOCK + tid;
        const int r5 = g % 5;                  // = (q+tid)%5, compiler folds
        const v4f v = {r5 == 0 ? 1.0f : 0.0f, 0.0f, r5 == 2 ? 1.0f : 0.0f, 0.0f};
        gout[g] = v;
    }

    // mask: lane-contiguous f4
    const float xr[4] = {xv.x, xv.y, xv.z, xv.w};
    const v4f mv = {xr[0] != 0.f ? 1.f : 0.f, xr[1] != 0.f ? 1.f : 0.f,
                    xr[2] != 0.f ? 1.f : 0.f, xr[3] != 0.f ? 1.f : 0.f};
    ((v4f*)(out + (size_t)NTOT * NB))[bt] = mv;

    // wave-local compaction into this wave's private list segment
    int c = 0;
    #pragma unroll
    for (int j = 0; j < 4; ++j) c += (xr[j] != 0.0f) ? 1 : 0;
    int incl = c;
    #pragma unroll
    for (int d = 1; d < 64; d <<= 1) {
        int n = __shfl_up(incl, d, 64);
        if (lane >= d) incl += n;
    }
    if (lane == 63) ((unsigned*)ws)[CNT_BASE + seg] = (unsigned)incl;  // wave total

    unsigned long long* wlist = (unsigned long long*)(ws + LIST_BASE) + (size_t)seg * 256;
    int off = incl - c;
    #pragma unroll
    for (int j = 0; j < 4; ++j) {
        if (xr[j] != 0.0f) {
            const unsigned eidx = 4u * (unsigned)bt + (unsigned)j;
            wlist[off++] = ((unsigned long long)eidx << 32) | (unsigned long long)__float_as_uint(xr[j]);
        }
    }
}

// ---------------- kernel 3: scatter softmax, one wave per segment ----------------
// Dispatch boundary provides defaults->overwrite WAW ordering.
__global__ __launch_bounds__(BLOCK) void scatter_kernel(
    const float* __restrict__ ws, float* __restrict__ out)
{
    __shared__ __align__(16) unsigned int sdata[SD_U32];   // ts | tab | buckets
    const int tid = threadIdx.x;
    #pragma unroll
    for (int q = tid; q < SD_U32 / 4; q += BLOCK)
        ((v4f*)sdata)[q] = ((const v4f*)ws)[q];
    __syncthreads();

    const float* ts  = (const float*)sdata;
    const float* tab = (const float*)sdata + 128;
    const unsigned char* buk = (const unsigned char*)(sdata + TAB_U32);

    const int lane = tid & 63;
    const int seg = blockIdx.x * 4 + (tid >> 6);           // 2500 blocks x 4 waves
    const unsigned cnt = ((const unsigned*)ws)[CNT_BASE + seg];
    const unsigned long long* wlist =
        (const unsigned long long*)(ws + LIST_BASE) + (size_t)seg * 256;

    for (unsigned i = lane; i < cnt; i += 64) {
        const unsigned long long pk = wlist[i];
        const unsigned e = (unsigned)(pk >> 32);
        const float xe = __uint_as_float((unsigned)pk);
        // bucket start (guaranteed <= region(xe)), then exact forward scan
        const float fb = fminf(2047.0f, fmaxf(0.0f, (xe - BLO) * BSCALE));
        int idx = buk[(int)fb];
        while (ts[idx] <= xe) ++idx;   // ts padded with SENT -> terminates, idx<=64
        const v4f* rowv = (const v4f*)(tab + idx * RSTRIDE);
        const v4f r0 = rowv[0], r1 = rowv[1], r2 = rowv[2], r3 = rowv[3], r4 = rowv[4];
        const float A[KB] = {r0.x, r0.y, r0.z, r0.w, r1.x, r1.y, r1.z, r1.w, r2.x};
        const float C[KB] = {r2.y, r2.z, r2.w, r3.x, r3.y, r3.z, r3.w, r4.x, r4.y};
        float lg[KB];   // base-2 logits (table pre-scaled by log2e)
        #pragma unroll
        for (int k = 0; k < KB; ++k) lg[k] = fmaf(A[k], xe, C[k]);
        float m = lg[0];
        #pragma unroll
        for (int k = 1; k < KB; ++k) m = fmaxf(m, lg[k]);
        float p[KB];
        float s = 0.0f;
        #pragma unroll
        for (int k = 0; k < KB; ++k) { p[k] = exp2f(lg[k] - m); s += p[k]; }
        const float rcp = __frcp_rn(s);
        v2f* po = (v2f*)(out + (size_t)e * NB);   // 8B-aligned (40e bytes)
        po[0] = (v2f){0.0f,       p[0] * rcp};
        po[1] = (v2f){p[1] * rcp, p[2] * rcp};
        po[2] = (v2f){p[3] * rcp, p[4] * rcp};
        po[3] = (v2f){p[5] * rcp, p[6] * rcp};
        po[4] = (v2f){p[7] * rcp, p[8] * rcp};
    }
}

// ---------------- fallback if d_ws too small: self-contained dense kernel ----------------
__global__ __launch_bounds__(BLOCK) void fused_kernel(
    const float* __restrict__ expr,
    const float* __restrict__ W1, const float* __restrict__ b1,
    const float* __restrict__ W2, const float* __restrict__ b2,
    float* __restrict__ out)
{
    __shared__ float ts[128];
    __shared__ float tab[65 * RSTRIDE];
    __shared__ float st[HID], sw[HID], sb[HID], tsrt[HID];
    const int tid = threadIdx.x;
    if (tid < HID) {
        float w = W1[tid], b = b1[tid];
        st[tid] = (w != 0.0f) ? (-b / w) : -SENT;
        sw[tid] = w; sb[tid] = b;
    }
    __syncthreads();
    if (tid < HID) {
        float t = st[tid];
        int r = 0;
        for (int i = 0; i < HID; ++i) {
            float ti = st[i];
            r += (ti < t || (ti == t && i < tid)) ? 1 : 0;
        }
        tsrt[r] = t;
    }
    __syncthreads();
    if (tid < 128) ts[tid] = (tid < HID) ? tsrt[tid] : SENT;
    for (int item = tid; item < 65 * KB; item += BLOCK) {
        int r = item / KB, k = item - r * KB;
        float xm;
        if (r == 0)        xm = tsrt[0] - 1.0f;
        else if (r == HID) xm = tsrt[HID - 1] + 1.0f;
        else               xm = 0.5f * (tsrt[r - 1] + tsrt[r]);
        float A = 0.0f, C = b2[k];
        for (int j = 0; j < HID; ++j) {
            float w = sw[j], bb = sb[j];
            float s = (fmaf(w, xm, bb) >= 0.0f) ? 1.0f : LEAKY;
            float w2s = W2[j * KB + k] * s;
            A = fmaf(w2s, w, A);
            C = fmaf(w2s, bb, C);
        }
        tab[r * RSTRIDE + k] = A;
        tab[r * RSTRIDE + KB + k] = C;
    }
    __syncthreads();
    const int i0 = (blockIdx.x * BLOCK + tid) * 2;
    const float2 xv = *(const float2*)(expr + i0);
    float x[2] = {xv.x, xv.y};
    float o[2 * NB]; float msk[2];
    #pragma unroll
    for (int e = 0; e < 2; ++e) {
        const float xe = x[e];
        int idx = 0;
        #pragma unroll
        for (int s = 64; s >= 1; s >>= 1) idx += (ts[idx + s - 1] <= xe) ? s : 0;
        const float* row = tab + idx * RSTRIDE;
        float lg[KB];
        #pragma unroll
        for (int k = 0; k < KB; ++k) lg[k] = fmaf(row[k], xe, row[KB + k]);
        float m = lg[0];
        #pragma unroll
        for (int k = 1; k < KB; ++k) m = fmaxf(m, lg[k]);
        float p[KB]; float s = 0.0f;
        #pragma unroll
        for (int k = 0; k < KB; ++k) { p[k] = __expf(lg[k] - m); s += p[k]; }
        const float rcp = __frcp_rn(s);
        const bool nz = (xe != 0.0f);
        msk[e] = nz ? 1.0f : 0.0f;
        o[e * NB] = nz ? 0.0f : 1.0f;
        #pragma unroll
        for (int k = 0; k < KB; ++k) o[e * NB + 1 + k] = nz ? p[k] * rcp : 0.0f;
    }
    float* dst = out + (size_t)i0 * NB;
    #pragma unroll
    for (int q = 0; q < 5; ++q) ((float4*)dst)[q] = ((const float4*)o)[q];
    *(float2*)(out + (size_t)NTOT * NB + i0) = make_float2(msk[0], msk[1]);
}

extern "C" void kernel_launch(void* const* d_in, const int* in_sizes, int n_in,
                              void* d_out, int out_size, void* d_ws, size_t ws_size,
                              hipStream_t stream) {
    const float* expr = (const float*)d_in[0];
    const float* W1   = (const float*)d_in[1];
    const float* b1   = (const float*)d_in[2];
    const float* W2   = (const float*)d_in[3];
    const float* b2   = (const float*)d_in[4];
    float* out = (float*)d_out;

    if (ws_size >= WS_BYTES) {
        float* ws = (float*)d_ws;
        setup_kernel<<<65 + NBUK / 64, 64, 0, stream>>>(W1, b1, W2, b2, ws);
        stream_kernel<<<NTOT / (BLOCK * 4), BLOCK, 0, stream>>>(expr, ws, out);   // 2500 blocks
        scatter_kernel<<<NSEG / 4, BLOCK, 0, stream>>>(ws, out);                  // 2500 blocks
    } else {
        fused_kernel<<<NTOT / (BLOCK * 2), BLOCK, 0, stream>>>(expr, W1, b1, W2, b2, out);
    }
}

// Round 15
// 141.527 us; speedup vs baseline: 1.7030x; 1.0442x over previous
//
#include <hip/hip_runtime.h>
#include <math.h>

#define HID 64
#define KB 9            // NUM_BINS - 1
#define NB 10
#define NTOT (128 * 20000)
#define BLOCK 256
#define EPB 2048        // elements per block (8 per thread)
#define LEAKY 0.01f
#define RSTRIDE 20      // floats per region row (9 A + 9 C + 2 pad) = 5 f4s
#define SENT 3.0e38f
#define LOG2E 1.44269504088896f

// bucket LUT for region search
#define NBUK 2048
#define BLO (-6.0f)
#define BSCALE (2048.0f / 12.0f)

#define TAB_U32 (128 + 65 * RSTRIDE)      // 1428 u32: 128 thresholds + 65 rows
#define SD_U32 (TAB_U32 + NBUK / 4)       // + 512 u32 of u8 buckets = 1940 (= 485 f4)
#define WS_BYTES (SD_U32 * 4)

typedef float v4f __attribute__((ext_vector_type(4)));
typedef float v2f __attribute__((ext_vector_type(2)));

// ---------------- setup: 97 blocks x 64 threads (unchanged since R9) ----------------
__global__ __launch_bounds__(64) void setup_kernel(
    const float* __restrict__ W1, const float* __restrict__ b1,
    const float* __restrict__ W2, const float* __restrict__ b2,
    float* __restrict__ ws)
{
    __shared__ float t_lds[HID], w_lds[HID], b_lds[HID], tsrt[HID];
    __shared__ float w2_lds[HID * KB];
    __shared__ float red[18 * 65];   // rows padded to 65 -> conflict-free reduce

    const int j = threadIdx.x;       // unit index (original order)
    const int blk = blockIdx.x;
    const float w = W1[j], b = b1[j];
    const float t = (w != 0.0f) ? (-b / w) : -SENT;  // w==0: constant sign, park at -inf
    t_lds[j] = t; w_lds[j] = w; b_lds[j] = b;
    if (blk < 65) {
        #pragma unroll
        for (int q = j; q < HID * KB; q += 64) w2_lds[q] = W2[q];
    }
    __syncthreads();

    int rank = 0;                    // rank sort (unique ranks via index tiebreak)
    for (int i = 0; i < HID; ++i) {
        float ti = t_lds[i];
        rank += (ti < t || (ti == t && i < j)) ? 1 : 0;
    }
    tsrt[rank] = t;
    __syncthreads();

    if (blk >= 65) {                 // bucket fill
        const int bb = (blk - 65) * 64 + j;
        const float edge = BLO + ((float)bb - 0.5f) * (1.0f / BSCALE);  // half-bucket margin
        int cnt = 0;
        for (int i = 0; i < HID; ++i) cnt += (tsrt[i] <= edge) ? 1 : 0;
        ((unsigned char*)(ws + TAB_U32))[bb] = (bb == 0) ? 0 : (unsigned char)cnt;
        return;
    }

    const int r = blk;               // region index 0..64
    float xm;                        // point strictly inside region r
    if (r == 0)        xm = tsrt[0] - 1.0f;
    else if (r == HID) xm = tsrt[HID - 1] + 1.0f;
    else               xm = 0.5f * (tsrt[r - 1] + tsrt[r]);

    const float s = (fmaf(w, xm, b) >= 0.0f) ? 1.0f : LEAKY;
    #pragma unroll
    for (int k = 0; k < KB; ++k) {
        const float w2s = w2_lds[j * KB + k] * s;
        red[(2 * k) * 65 + j]     = w2s * w;   // A contribution
        red[(2 * k + 1) * 65 + j] = w2s * b;   // C contribution
    }
    __syncthreads();

    if (j < 18) {   // threads 0..17 each sum one row of 64 (deterministic order)
        float acc = 0.0f;
        for (int i = 0; i < HID; ++i) acc += red[j * 65 + i];
        const int k = j >> 1;
        if (j & 1) ws[128 + r * RSTRIDE + KB + k] = (acc + b2[k]) * LOG2E;  // C'
        else       ws[128 + r * RSTRIDE + k]      = acc * LOG2E;            // A'
    }
    if (r == 0) { ws[j] = tsrt[j]; ws[64 + j] = SENT; }
}

// ---------------- main: R11 minus compaction — one barrier, divergent phase 2 ----------------
// Phase 1: stage table, load 8 expr/thread, write defaults lane-major + mask.
// __syncthreads (compiler drains vmcnt before s_barrier -> defaults at L2 =
// WAW order vs phase 2; also covers table staging).
// Phase 2: each thread softmax-overwrites its own nonzeros from registers.
// Divergence cost ~8 body-runs/wave (~72 extra trans-instr) ~= +1 us chip-wide,
// cheaper than the 12 KB LDS + scan + extra barrier it replaces.
__global__ __launch_bounds__(BLOCK) void main_kernel(
    const float* __restrict__ expr, const float* __restrict__ ws,
    float* __restrict__ out)
{
    __shared__ __align__(16) unsigned int sdata[SD_U32];   // ts | tab | buckets (7.8 KB)
    const int tid = threadIdx.x;
    #pragma unroll
    for (int t = tid; t < SD_U32 / 4; t += BLOCK)
        ((v4f*)sdata)[t] = ((const v4f*)ws)[t];

    const size_t e0 = (size_t)blockIdx.x * EPB;
    const v4f xa = ((const v4f*)(expr + e0))[tid];
    const v4f xb = ((const v4f*)(expr + e0))[BLOCK + tid];
    const float xr[8] = {xa.x, xa.y, xa.z, xa.w, xb.x, xb.y, xb.z, xb.w};

    // default probs: 2048 elems = 5120 f4s, lane-major; tile base 20480-float
    // aligned so f4 g: g%5==0 -> {1,0,0,0}; g%5==2 -> {0,0,1,0}; else zeros.
    float* gout = out + e0 * NB;
    #pragma unroll
    for (int q = 0; q < 20; ++q) {
        const int g = q * BLOCK + tid;
        const int r5 = g % 5;        // = (q+tid)%5, compiler folds
        const v4f v = {r5 == 0 ? 1.0f : 0.0f, 0.0f, r5 == 2 ? 1.0f : 0.0f, 0.0f};
        ((v4f*)gout)[g] = v;
    }

    // mask: lane-contiguous f4
    float* mout = out + (size_t)NTOT * NB + e0;
    const v4f ma = {xr[0] != 0.f ? 1.f : 0.f, xr[1] != 0.f ? 1.f : 0.f,
                    xr[2] != 0.f ? 1.f : 0.f, xr[3] != 0.f ? 1.f : 0.f};
    const v4f mb = {xr[4] != 0.f ? 1.f : 0.f, xr[5] != 0.f ? 1.f : 0.f,
                    xr[6] != 0.f ? 1.f : 0.f, xr[7] != 0.f ? 1.f : 0.f};
    ((v4f*)mout)[tid] = ma;
    ((v4f*)mout)[BLOCK + tid] = mb;

    __syncthreads();   // defaults drained to L2 (WAW) + table visible

    const float* ts  = (const float*)sdata;
    const float* tab = (const float*)sdata + 128;
    const unsigned char* buk = (const unsigned char*)(sdata + TAB_U32);

    #pragma unroll
    for (int j = 0; j < 8; ++j) {
        const float xe = xr[j];
        if (xe != 0.0f) {
            // bucket start (guaranteed <= region(xe)), then exact forward scan
            const float fb = fminf(2047.0f, fmaxf(0.0f, (xe - BLO) * BSCALE));
            int idx = buk[(int)fb];
            while (ts[idx] <= xe) ++idx;   // ts padded with SENT -> terminates, idx<=64
            const v4f* rowv = (const v4f*)(tab + idx * RSTRIDE);
            const v4f r0 = rowv[0], r1 = rowv[1], r2 = rowv[2], r3 = rowv[3], r4 = rowv[4];
            const float A[KB] = {r0.x, r0.y, r0.z, r0.w, r1.x, r1.y, r1.z, r1.w, r2.x};
            const float C[KB] = {r2.y, r2.z, r2.w, r3.x, r3.y, r3.z, r3.w, r4.x, r4.y};
            float lg[KB];   // base-2 logits (table pre-scaled by log2e)
            #pragma unroll
            for (int k = 0; k < KB; ++k) lg[k] = fmaf(A[k], xe, C[k]);
            float m = lg[0];
            #pragma unroll
            for (int k = 1; k < KB; ++k) m = fmaxf(m, lg[k]);
            float p[KB];
            float s = 0.0f;
            #pragma unroll
            for (int k = 0; k < KB; ++k) { p[k] = exp2f(lg[k] - m); s += p[k]; }
            const float rcp = __frcp_rn(s);
            const int eidx = (j < 4) ? (4 * tid + j) : (1024 + 4 * tid + (j - 4));
            v2f* po = (v2f*)(gout + (size_t)eidx * NB);   // 8B-aligned
            po[0] = (v2f){0.0f,       p[0] * rcp};
            po[1] = (v2f){p[1] * rcp, p[2] * rcp};
            po[2] = (v2f){p[3] * rcp, p[4] * rcp};
            po[3] = (v2f){p[5] * rcp, p[6] * rcp};
            po[4] = (v2f){p[7] * rcp, p[8] * rcp};
        }
    }
}

// ---------------- fallback if d_ws too small: self-contained dense kernel ----------------
__global__ __launch_bounds__(BLOCK) void fused_kernel(
    const float* __restrict__ expr,
    const float* __restrict__ W1, const float* __restrict__ b1,
    const float* __restrict__ W2, const float* __restrict__ b2,
    float* __restrict__ out)
{
    __shared__ float ts[128];
    __shared__ float tab[65 * RSTRIDE];
    __shared__ float st[HID], sw[HID], sb[HID], tsrt[HID];
    const int tid = threadIdx.x;
    if (tid < HID) {
        float w = W1[tid], b = b1[tid];
        st[tid] = (w != 0.0f) ? (-b / w) : -SENT;
        sw[tid] = w; sb[tid] = b;
    }
    __syncthreads();
    if (tid < HID) {
        float t = st[tid];
        int r = 0;
        for (int i = 0; i < HID; ++i) {
            float ti = st[i];
            r += (ti < t || (ti == t && i < tid)) ? 1 : 0;
        }
        tsrt[r] = t;
    }
    __syncthreads();
    if (tid < 128) ts[tid] = (tid < HID) ? tsrt[tid] : SENT;
    for (int item = tid; item < 65 * KB; item += BLOCK) {
        int r = item / KB, k = item - r * KB;
        float xm;
        if (r == 0)        xm = tsrt[0] - 1.0f;
        else if (r == HID) xm = tsrt[HID - 1] + 1.0f;
        else               xm = 0.5f * (tsrt[r - 1] + tsrt[r]);
        float A = 0.0f, C = b2[k];
        for (int j = 0; j < HID; ++j) {
            float w = sw[j], bb = sb[j];
            float s = (fmaf(w, xm, bb) >= 0.0f) ? 1.0f : LEAKY;
            float w2s = W2[j * KB + k] * s;
            A = fmaf(w2s, w, A);
            C = fmaf(w2s, bb, C);
        }
        tab[r * RSTRIDE + k] = A;
        tab[r * RSTRIDE + KB + k] = C;
    }
    __syncthreads();
    const int i0 = (blockIdx.x * BLOCK + tid) * 2;
    const float2 xv = *(const float2*)(expr + i0);
    float x[2] = {xv.x, xv.y};
    float o[2 * NB]; float msk[2];
    #pragma unroll
    for (int e = 0; e < 2; ++e) {
        const float xe = x[e];
        int idx = 0;
        #pragma unroll
        for (int s = 64; s >= 1; s >>= 1) idx += (ts[idx + s - 1] <= xe) ? s : 0;
        const float* row = tab + idx * RSTRIDE;
        float lg[KB];
        #pragma unroll
        for (int k = 0; k < KB; ++k) lg[k] = fmaf(row[k], xe, row[KB + k]);
        float m = lg[0];
        #pragma unroll
        for (int k = 1; k < KB; ++k) m = fmaxf(m, lg[k]);
        float p[KB]; float s = 0.0f;
        #pragma unroll
        for (int k = 0; k < KB; ++k) { p[k] = __expf(lg[k] - m); s += p[k]; }
        const float rcp = __frcp_rn(s);
        const bool nz = (xe != 0.0f);
        msk[e] = nz ? 1.0f : 0.0f;
        o[e * NB] = nz ? 0.0f : 1.0f;
        #pragma unroll
        for (int k = 0; k < KB; ++k) o[e * NB + 1 + k] = nz ? p[k] * rcp : 0.0f;
    }
    float* dst = out + (size_t)i0 * NB;
    #pragma unroll
    for (int q = 0; q < 5; ++q) ((float4*)dst)[q] = ((const float4*)o)[q];
    *(float2*)(out + (size_t)NTOT * NB + i0) = make_float2(msk[0], msk[1]);
}

extern "C" void kernel_launch(void* const* d_in, const int* in_sizes, int n_in,
                              void* d_out, int out_size, void* d_ws, size_t ws_size,
                              hipStream_t stream) {
    const float* expr = (const float*)d_in[0];
    const float* W1   = (const float*)d_in[1];
    const float* b1   = (const float*)d_in[2];
    const float* W2   = (const float*)d_in[3];
    const float* b2   = (const float*)d_in[4];
    float* out = (float*)d_out;

    if (ws_size >= (size_t)WS_BYTES) {
        float* ws = (float*)d_ws;
        setup_kernel<<<65 + NBUK / 64, 64, 0, stream>>>(W1, b1, W2, b2, ws);
        main_kernel<<<NTOT / EPB, BLOCK, 0, stream>>>(expr, ws, out);   // 1250 blocks
    } else {
        fused_kernel<<<NTOT / (BLOCK * 2), BLOCK, 0, stream>>>(expr, W1, b1, W2, b2, out);
    }
}

// Round 16
// 138.911 us; speedup vs baseline: 1.7351x; 1.0188x over previous
//
#include <hip/hip_runtime.h>
#include <math.h>

#define HID 64
#define KB 9            // NUM_BINS - 1
#define NB 10
#define NTOT (128 * 20000)
#define BLOCK 256
#define EPB 2048        // elements per block (main kernel)
#define FEPT 2          // fallback kernel elements/thread
#define LEAKY 0.01f
#define RSTRIDE 20      // floats per region row (9 A + 9 C + 2 pad) = 5 f4s
#define SENT 3.0e38f
#define LOG2E 1.44269504088896f

// bucket LUT for region search
#define NBUK 2048
#define BLO (-6.0f)
#define BSCALE (2048.0f / 12.0f)

#define TAB_U32 (128 + 65 * RSTRIDE)      // 1428 u32: 128 thresholds + 65 rows
#define WS_U32 (TAB_U32 + NBUK / 4)       // + 512 u32 of u8 buckets = 1940 (= 485 f4)
#define WS_BYTES (WS_U32 * 4)

typedef float v4f __attribute__((ext_vector_type(4)));
typedef float v2f __attribute__((ext_vector_type(2)));

// ---------------- setup: 97 blocks x 64 threads (unchanged since R9) ----------------
__global__ __launch_bounds__(64) void setup_kernel(
    const float* __restrict__ W1, const float* __restrict__ b1,
    const float* __restrict__ W2, const float* __restrict__ b2,
    float* __restrict__ ws)
{
    __shared__ float t_lds[HID], w_lds[HID], b_lds[HID], tsrt[HID];
    __shared__ float w2_lds[HID * KB];
    __shared__ float red[18 * 65];   // rows padded to 65 -> conflict-free reduce

    const int j = threadIdx.x;       // unit index (original order)
    const int blk = blockIdx.x;
    const float w = W1[j], b = b1[j];
    const float t = (w != 0.0f) ? (-b / w) : -SENT;  // w==0: constant sign, park at -inf
    t_lds[j] = t; w_lds[j] = w; b_lds[j] = b;
    if (blk < 65) {
        #pragma unroll
        for (int q = j; q < HID * KB; q += 64) w2_lds[q] = W2[q];
    }
    __syncthreads();

    int rank = 0;                    // rank sort (unique ranks via index tiebreak)
    for (int i = 0; i < HID; ++i) {
        float ti = t_lds[i];
        rank += (ti < t || (ti == t && i < j)) ? 1 : 0;
    }
    tsrt[rank] = t;
    __syncthreads();

    if (blk >= 65) {                 // bucket fill
        const int bb = (blk - 65) * 64 + j;
        const float edge = BLO + ((float)bb - 0.5f) * (1.0f / BSCALE);  // half-bucket margin
        int cnt = 0;
        for (int i = 0; i < HID; ++i) cnt += (tsrt[i] <= edge) ? 1 : 0;
        ((unsigned char*)(ws + TAB_U32))[bb] = (bb == 0) ? 0 : (unsigned char)cnt;
        return;
    }

    const int r = blk;               // region index 0..64
    float xm;                        // point strictly inside region r
    if (r == 0)        xm = tsrt[0] - 1.0f;
    else if (r == HID) xm = tsrt[HID - 1] + 1.0f;
    else               xm = 0.5f * (tsrt[r - 1] + tsrt[r]);

    const float s = (fmaf(w, xm, b) >= 0.0f) ? 1.0f : LEAKY;
    #pragma unroll
    for (int k = 0; k < KB; ++k) {
        const float w2s = w2_lds[j * KB + k] * s;
        red[(2 * k) * 65 + j]     = w2s * w;   // A contribution
        red[(2 * k + 1) * 65 + j] = w2s * b;   // C contribution
    }
    __syncthreads();

    if (j < 18) {   // threads 0..17 each sum one row of 64 (deterministic order)
        float acc = 0.0f;
        for (int i = 0; i < HID; ++i) acc += red[j * 65 + i];
        const int k = j >> 1;
        if (j & 1) ws[128 + r * RSTRIDE + KB + k] = (acc + b2[k]) * LOG2E;  // C'
        else       ws[128 + r * RSTRIDE + k]      = acc * LOG2E;            // A'
    }
    if (r == 0) { ws[j] = tsrt[j]; ws[64 + j] = SENT; }
}

// ---------------- main: R11 compacted two-phase, default-store burst hoisted first ----------------
// Order: table staging -> DEFAULT STORES (constant, dependency-free: max head
// start, R14 lesson) -> expr load/stash -> mask -> shfl scan -> barrier1
// (drains the head-started stores; xs+swsum visible) -> list write -> barrier2
// (LDS-only; vmcnt already drained = free) -> compacted softmax scatter.
__global__ __launch_bounds__(BLOCK) void main_kernel(
    const float* __restrict__ expr, const float* __restrict__ ws,
    float* __restrict__ out)
{
    __shared__ __align__(16) unsigned int sdata[WS_U32];   // ts | tab | buckets
    __shared__ float xs[EPB];
    __shared__ unsigned short list[EPB];
    __shared__ int swsum[4];

    const int tid = threadIdx.x;
    const int lane = tid & 63, wv = tid >> 6;

    // stage tables once per block
    #pragma unroll
    for (int t = tid; t < WS_U32 / 4; t += BLOCK)
        ((v4f*)sdata)[t] = ((const v4f*)ws)[t];

    // default probs FIRST: constant zero-element pattern, lane-major linear f4s.
    // f4 g covers floats 4g..4g+3; 1 appears iff (4g+c)%10==0:
    // g%5==0 -> {1,0,0,0}; g%5==2 -> {0,0,1,0}; else zeros.
    const size_t e0 = (size_t)blockIdx.x * EPB;
    float* gout = out + e0 * NB;
    #pragma unroll
    for (int q = 0; q < 20; ++q) {
        const int g = q * BLOCK + tid;
        const int r5 = g % 5;        // (q*256+t)%5 == (q+t)%5; compiler folds
        const v4f v = {r5 == 0 ? 1.0f : 0.0f, 0.0f, r5 == 2 ? 1.0f : 0.0f, 0.0f};
        ((v4f*)gout)[g] = v;
    }

    // block's 2048 expr floats: 2 coalesced f4 loads/thread; stash to LDS
    const v4f xa = ((const v4f*)(expr + e0))[tid];
    const v4f xb = ((const v4f*)(expr + e0))[BLOCK + tid];
    ((v4f*)xs)[tid] = xa;
    ((v4f*)xs)[BLOCK + tid] = xb;
    const float xr[8] = {xa.x, xa.y, xa.z, xa.w, xb.x, xb.y, xb.z, xb.w};

    // mask output: element-coalesced f4 stores
    float* mout = out + (size_t)NTOT * NB + e0;
    const v4f ma = {xr[0] != 0.f ? 1.f : 0.f, xr[1] != 0.f ? 1.f : 0.f,
                    xr[2] != 0.f ? 1.f : 0.f, xr[3] != 0.f ? 1.f : 0.f};
    const v4f mb = {xr[4] != 0.f ? 1.f : 0.f, xr[5] != 0.f ? 1.f : 0.f,
                    xr[6] != 0.f ? 1.f : 0.f, xr[7] != 0.f ? 1.f : 0.f};
    ((v4f*)mout)[tid] = ma;
    ((v4f*)mout)[BLOCK + tid] = mb;

    int c = 0;
    #pragma unroll
    for (int j = 0; j < 8; ++j) c += (xr[j] != 0.0f) ? 1 : 0;

    // wave-inclusive scan of per-thread counts
    int incl = c;
    #pragma unroll
    for (int d = 1; d < 64; d <<= 1) {
        int n = __shfl_up(incl, d, 64);
        if (lane >= d) incl += n;
    }
    if (lane == 63) swsum[wv] = incl;
    __syncthreads();                 // barrier1: xs+swsum visible; store burst drains here

    const int s0 = swsum[0], s1 = swsum[1], s2 = swsum[2], s3 = swsum[3];
    const int total = s0 + s1 + s2 + s3;
    int base = (incl - c) + (wv > 0 ? s0 : 0) + (wv > 1 ? s1 : 0) + (wv > 2 ? s2 : 0);

    #pragma unroll
    for (int j = 0; j < 8; ++j) {
        if (xr[j] != 0.0f) {
            const int eidx = (j < 4) ? (4 * tid + j) : (1024 + 4 * tid + (j - 4));
            list[base++] = (unsigned short)eidx;
        }
    }

    __syncthreads();   // barrier2: list visible (LDS-only; vmcnt already 0)

    const float* ts  = (const float*)sdata;
    const float* tab = (const float*)sdata + 128;
    const unsigned char* buk = (const unsigned char*)(sdata + TAB_U32);

    for (int i = tid; i < total; i += BLOCK) {
        const int e = list[i];
        const float xe = xs[e];
        // bucket start (guaranteed <= region(xe)), then exact forward scan
        const float fb = fminf(2047.0f, fmaxf(0.0f, (xe - BLO) * BSCALE));
        int idx = buk[(int)fb];
        while (ts[idx] <= xe) ++idx;   // ts padded with SENT -> terminates, idx<=64
        const v4f* rowv = (const v4f*)(tab + idx * RSTRIDE);
        const v4f r0 = rowv[0], r1 = rowv[1], r2 = rowv[2], r3 = rowv[3], r4 = rowv[4];
        const float A[KB] = {r0.x, r0.y, r0.z, r0.w, r1.x, r1.y, r1.z, r1.w, r2.x};
        const float C[KB] = {r2.y, r2.z, r2.w, r3.x, r3.y, r3.z, r3.w, r4.x, r4.y};
        float lg[KB];   // base-2 logits (table pre-scaled by log2e)
        #pragma unroll
        for (int k = 0; k < KB; ++k) lg[k] = fmaf(A[k], xe, C[k]);
        float m = lg[0];
        #pragma unroll
        for (int k = 1; k < KB; ++k) m = fmaxf(m, lg[k]);
        float p[KB];
        float s = 0.0f;
        #pragma unroll
        for (int k = 0; k < KB; ++k) { p[k] = exp2f(lg[k] - m); s += p[k]; }
        const float rcp = __frcp_rn(s);
        // scatter: elem e's 10 floats = 5 float2 (8B-aligned: 40e bytes)
        v2f* po = (v2f*)(gout + (size_t)e * NB);
        po[0] = (v2f){0.0f,        p[0] * rcp};
        po[1] = (v2f){p[1] * rcp,  p[2] * rcp};
        po[2] = (v2f){p[3] * rcp,  p[4] * rcp};
        po[3] = (v2f){p[5] * rcp,  p[6] * rcp};
        po[4] = (v2f){p[7] * rcp,  p[8] * rcp};
    }
}

// ---------------- fallback if d_ws too small: self-contained, per-block table ----------------
__global__ __launch_bounds__(BLOCK) void fused_kernel(
    const float* __restrict__ expr,
    const float* __restrict__ W1, const float* __restrict__ b1,
    const float* __restrict__ W2, const float* __restrict__ b2,
    float* __restrict__ out)
{
    __shared__ float ts[128];
    __shared__ float tab[65 * RSTRIDE];
    __shared__ float st[HID], sw[HID], sb[HID], tsrt[HID];
    const int tid = threadIdx.x;
    if (tid < HID) {
        float w = W1[tid], b = b1[tid];
        st[tid] = (w != 0.0f) ? (-b / w) : -SENT;
        sw[tid] = w; sb[tid] = b;
    }
    __syncthreads();
    if (tid < HID) {
        float t = st[tid];
        int r = 0;
        for (int i = 0; i < HID; ++i) {
            float ti = st[i];
            r += (ti < t || (ti == t && i < tid)) ? 1 : 0;
        }
        tsrt[r] = t;
    }
    __syncthreads();
    if (tid < 128) ts[tid] = (tid < HID) ? tsrt[tid] : SENT;
    for (int item = tid; item < 65 * KB; item += BLOCK) {
        int r = item / KB, k = item - r * KB;
        float xm;
        if (r == 0)        xm = tsrt[0] - 1.0f;
        else if (r == HID) xm = tsrt[HID - 1] + 1.0f;
        else               xm = 0.5f * (tsrt[r - 1] + tsrt[r]);
        float A = 0.0f, C = b2[k];
        for (int j = 0; j < HID; ++j) {
            float w = sw[j], bb = sb[j];
            float s = (fmaf(w, xm, bb) >= 0.0f) ? 1.0f : LEAKY;
            float w2s = W2[j * KB + k] * s;
            A = fmaf(w2s, w, A);
            C = fmaf(w2s, bb, C);
        }
        tab[r * RSTRIDE + k] = A;
        tab[r * RSTRIDE + KB + k] = C;
    }
    __syncthreads();
    const int i0 = (blockIdx.x * BLOCK + tid) * FEPT;
    const float2 xv = *(const float2*)(expr + i0);
    float x[FEPT] = {xv.x, xv.y};
    float o[FEPT * NB]; float msk[FEPT];
    #pragma unroll
    for (int e = 0; e < FEPT; ++e) {
        const float xe = x[e];
        int idx = 0;
        #pragma unroll
        for (int s = 64; s >= 1; s >>= 1) idx += (ts[idx + s - 1] <= xe) ? s : 0;
        const float* row = tab + idx * RSTRIDE;
        float lg[KB];
        #pragma unroll
        for (int k = 0; k < KB; ++k) lg[k] = fmaf(row[k], xe, row[KB + k]);
        float m = lg[0];
        #pragma unroll
        for (int k = 1; k < KB; ++k) m = fmaxf(m, lg[k]);
        float p[KB]; float s = 0.0f;
        #pragma unroll
        for (int k = 0; k < KB; ++k) { p[k] = __expf(lg[k] - m); s += p[k]; }
        const float rcp = __frcp_rn(s);
        const bool nz = (xe != 0.0f);
        msk[e] = nz ? 1.0f : 0.0f;
        o[e * NB] = nz ? 0.0f : 1.0f;
        #pragma unroll
        for (int k = 0; k < KB; ++k) o[e * NB + 1 + k] = nz ? p[k] * rcp : 0.0f;
    }
    float* dst = out + (size_t)i0 * NB;
    #pragma unroll
    for (int q = 0; q < FEPT * NB / 4; ++q) ((float4*)dst)[q] = ((const float4*)o)[q];
    *(float2*)(out + (size_t)NTOT * NB + i0) = make_float2(msk[0], msk[1]);
}

extern "C" void kernel_launch(void* const* d_in, const int* in_sizes, int n_in,
                              void* d_out, int out_size, void* d_ws, size_t ws_size,
                              hipStream_t stream) {
    const float* expr = (const float*)d_in[0];
    const float* W1   = (const float*)d_in[1];
    const float* b1   = (const float*)d_in[2];
    const float* W2   = (const float*)d_in[3];
    const float* b2   = (const float*)d_in[4];
    float* out = (float*)d_out;

    if (ws_size >= (size_t)WS_BYTES) {
        float* ws = (float*)d_ws;
        setup_kernel<<<65 + NBUK / 64, 64, 0, stream>>>(W1, b1, W2, b2, ws);
        main_kernel<<<NTOT / EPB, BLOCK, 0, stream>>>(expr, ws, out);   // 1250 blocks
    } else {
        fused_kernel<<<NTOT / (BLOCK * FEPT), BLOCK, 0, stream>>>(expr, W1, b1, W2, b2, out);
    }
}